// Round 9
// baseline (608.954 us; speedup 1.0000x reference)
//
#include <hip/hip_runtime.h>

typedef __attribute__((ext_vector_type(8))) short bf16x8;
typedef __attribute__((ext_vector_type(4))) float f32x4;

#define TEMP_ 30.0f
#define MFMA(A,B,C) __builtin_amdgcn_mfma_f32_16x16x32_bf16(A,B,C,0,0,0)

static __device__ inline unsigned short f2bf(float f) {
    unsigned u = __builtin_bit_cast(unsigned, f);
    u = (u + 0x7FFFu + ((u >> 16) & 1u)) >> 16;   // RNE
    return (unsigned short)u;
}
static __device__ inline unsigned packbf(float a, float b) {
    return (unsigned)f2bf(a) | ((unsigned)f2bf(b) << 16);
}
static __device__ inline bf16x8 bc16(uint4 v) { return __builtin_bit_cast(bf16x8, v); }

// ---------- kernel 1: GAP + fp32 NCHW -> bf16 NHWC transpose ----------
// grid (64, 16): 4-row slab per b; 256 thr (4 waves = 4 rows)
#define SM_S 1034   // per-c plane stride in shorts (4*258+2): 4*S%32==8 -> cg groups spread banks
__global__ __launch_bounds__(256) void gap_cvt_kernel(
    const float* __restrict__ x, float* __restrict__ gap,
    unsigned short* __restrict__ xbf)        // [16][256][256][32] bf16
{
    __shared__ unsigned short sm[32 * SM_S];
    __shared__ float red[4][32];
    int b = blockIdx.y, ys = blockIdx.x * 4;
    int t = threadIdx.x, wv = t >> 6, ln = t & 63;

    const float* xb = x + (((size_t)b * 32) << 16) + ((size_t)(ys + wv) << 8) + ln * 4;
    float part[32];
#pragma unroll
    for (int c = 0; c < 32; ++c) {
        float4 v = *(const float4*)(xb + ((size_t)c << 16));
        part[c] = v.x + v.y + v.z + v.w;
        unsigned* wp = (unsigned*)&sm[c * SM_S + wv * 258 + ln * 4];
        wp[0] = packbf(v.x, v.y);
        wp[1] = packbf(v.z, v.w);
    }
#pragma unroll
    for (int c = 0; c < 32; ++c) {
#pragma unroll
        for (int off = 32; off; off >>= 1) part[c] += __shfl_xor(part[c], off);
    }
    if (ln == 0) {
#pragma unroll
        for (int c = 0; c < 32; ++c) red[wv][c] = part[c];
    }
    __syncthreads();
    if (t < 32) {
        float s = red[0][t] + red[1][t] + red[2][t] + red[3][t];
        atomicAdd(&gap[b * 32 + t], s * (1.f / 65536.f));
    }
    // phase B: coalesced NHWC write. g = it*256+t -> uint4 index base+g (1KB/wave)
    uint4* outp = (uint4*)xbf;
    size_t base = (((size_t)b << 16) + ((size_t)ys << 8)) << 2;
#pragma unroll
    for (int it = 0; it < 16; ++it) {
        int g = it * 256 + t;
        int cgq = g & 3, px = g >> 2;          // px 0..1023 in slab
        int y = px >> 8, xx = px & 255;
        unsigned short h[8];
#pragma unroll
        for (int i = 0; i < 8; ++i) h[i] = sm[(cgq * 8 + i) * SM_S + y * 258 + xx];
        uint4 v;
        v.x = (unsigned)h[0] | ((unsigned)h[1] << 16);
        v.y = (unsigned)h[2] | ((unsigned)h[3] << 16);
        v.z = (unsigned)h[4] | ((unsigned)h[5] << 16);
        v.w = (unsigned)h[6] | ((unsigned)h[7] << 16);
        outp[base + g] = v;
    }
}

// ------- control MLP + softmax + blended weights -> bf16 [b][9][o(32)][c(32)] -------
__global__ __launch_bounds__(256) void assemble_kernel(
    const float* __restrict__ gap,
    const float* __restrict__ w_c1,   // [8][32]
    const float* __restrict__ w_c2,   // [128][8]
    const float* __restrict__ wt1,    // [4][32][288], inner j = c*9 + dy*3+dx
    const float* __restrict__ wt2,
    const float* __restrict__ wt3,
    unsigned short* __restrict__ wo1,
    unsigned short* __restrict__ wo2,
    unsigned short* __restrict__ wo3)
{
    int b = blockIdx.x;
    int sel = blockIdx.y;
    int t = threadIdx.x;
    __shared__ float gap_s[32], h_s[8], logit_s[128], coeff_s[32][4];
    if (t < 32) gap_s[t] = gap[b * 32 + t];
    __syncthreads();
    if (t < 8) {
        float a = 0.f;
        for (int c = 0; c < 32; ++c) a += gap_s[c] * w_c1[t * 32 + c];
        h_s[t] = a > 0.f ? a : 0.f;
    }
    __syncthreads();
    if (t < 128) {
        float a = 0.f;
        for (int k = 0; k < 8; ++k) a += h_s[k] * w_c2[t * 8 + k];
        logit_s[t] = a * (1.0f / TEMP_);
    }
    __syncthreads();
    if (t < 32) {
        float m = -1e30f;
        for (int e = 0; e < 4; ++e) m = fmaxf(m, logit_s[t * 4 + e]);
        float ex[4], sum = 0.f;
        for (int e = 0; e < 4; ++e) { ex[e] = expf(logit_s[t * 4 + e] - m); sum += ex[e]; }
        for (int e = 0; e < 4; ++e) coeff_s[t][e] = ex[e] / sum;
    }
    __syncthreads();

    const float* wt = sel == 0 ? wt1 : (sel == 1 ? wt2 : wt3);
    unsigned short* wo = sel == 0 ? wo1 : (sel == 1 ? wo2 : wo3);

    for (int idx = t; idx < 9216; idx += 256) {   // idx = d*1024 + o*32 + c
        int d = idx >> 10;
        int o = (idx >> 5) & 31;
        int c = idx & 31;
        int j = c * 9 + d;
        float v = coeff_s[o][0] * wt[(0 * 32 + o) * 288 + j]
                + coeff_s[o][1] * wt[(1 * 32 + o) * 288 + j]
                + coeff_s[o][2] * wt[(2 * 32 + o) * 288 + j]
                + coeff_s[o][3] * wt[(3 * 32 + o) * 288 + j];
        wo[(size_t)b * 9216 + idx] = f2bf(v);
    }
}

// ------------- fused conv1->conv2->conv3, intermediates in LDS -------------
// PLANAR LDS: 4 planes of 8 channels (16B granule) per buffer -> conflict-free
// b128 reads (4x256B contiguous per wave) and uint2 writes.
// bufA: plane p at uint4 ofs p*836, [22][38].  buf1: 3344 + p*960, [20][48].
// buf2 (aliases bufA): p*612, [18][34].
// Chained pad=1: intermediates outside [0,256)^2 are ZEROED.
// grid (8,16,16), 1024 thr (16 waves), LDS ~115KB -> 1 block/CU, 4 waves/SIMD.
__global__ __launch_bounds__(1024, 4) void fused_conv3(
    const unsigned short* __restrict__ xbf,   // [16][256][256][32]
    const unsigned short* __restrict__ w1,    // [16][9][32][32]
    const unsigned short* __restrict__ w2,
    const unsigned short* __restrict__ w3,
    float* __restrict__ out)                  // [16][32][256][256]
{
    __shared__ uint4 lds[7192];   // [0,3344) bufA; [3344,7184) buf1; pad
    int b  = blockIdx.z;
    int x0 = blockIdx.x * 32, y0 = blockIdx.y * 16;
    int t  = threadIdx.x;
    int l15 = t & 15, kg = (t >> 4) & 3, wv = t >> 6;   // wv 0..15

    const uint4* wp1 = (const uint4*)(w1 + (size_t)b * 9216);
    const uint4* wp2 = (const uint4*)(w2 + (size_t)b * 9216);
    const uint4* wp3 = (const uint4*)(w3 + (size_t)b * 9216);

    bf16x8 wfA[9][2], wfB[9][2];
#pragma unroll
    for (int d = 0; d < 9; ++d) {              // conv1 weights
        wfA[d][0] = bc16(wp1[(d * 32 + l15) * 4 + kg]);
        wfA[d][1] = bc16(wp1[(d * 32 + 16 + l15) * 4 + kg]);
    }

    // stage 38x22 tile -> bufA planes. tau = px*4+cg keeps global reads coalesced;
    // LDS uint4 idx = cg*836 + px (16 px x 4 planes per wave: 4x256B contiguous).
    const unsigned short* xb = xbf + (((size_t)b) << 16) * 32;
#pragma unroll
    for (int it = 0; it < 4; ++it) {
        int tau = it * 1024 + t;
        if (tau < 3344) {
            int px = tau >> 2, cg = tau & 3;
            int y = px / 38, xx = px - y * 38;
            int gy = y0 - 3 + y, gx = x0 - 3 + xx;
            uint4 v = make_uint4(0u, 0u, 0u, 0u);
            if ((unsigned)gy < 256u && (unsigned)gx < 256u)
                v = *(const uint4*)(xb + ((((size_t)gy << 8) + gx) << 5) + (cg << 3));
            lds[cg * 836 + px] = v;
        }
    }
#pragma unroll
    for (int d = 0; d < 9; ++d) {              // conv2 weights prefetch
        wfB[d][0] = bc16(wp2[(d * 32 + l15) * 4 + kg]);
        wfB[d][1] = bc16(wp2[(d * 32 + 16 + l15) * 4 + kg]);
    }
    __syncthreads();

    const bf16x8* LA = (const bf16x8*)lds;
    const bf16x8* L1 = (const bf16x8*)(lds + 3344);
    unsigned short* SA = (unsigned short*)lds;
    unsigned short* S1 = (unsigned short*)(lds + 3344);
    int pl0 = kg >> 1, half = (kg & 1) << 2;   // write plane pair / 8B half

    // ---- conv1: 20 rows x 3 xtiles (48 wide; X'<36 real) ----
    for (int i = wv; i < 60; i += 16) {
        int row = i / 3, xt = i - row * 3;
        int Xp = xt * 16 + l15;
        int base = kg * 836 + row * 38 + Xp;
        f32x4 a0 = {0.f,0.f,0.f,0.f}, a1 = {0.f,0.f,0.f,0.f};
#pragma unroll
        for (int d = 0; d < 9; ++d) {
            bf16x8 bfr = LA[base + (d / 3) * 38 + (d % 3)];
            a0 = MFMA(wfA[d][0], bfr, a0);
            a1 = MFMA(wfA[d][1], bfr, a1);
        }
        bool live = ((unsigned)(y0 - 2 + row) < 256u) && ((unsigned)(x0 - 2 + Xp) < 256u);
        uint2 p0, p1;
        p0.x = packbf(a0[0], a0[1]); p0.y = packbf(a0[2], a0[3]);
        p1.x = packbf(a1[0], a1[1]); p1.y = packbf(a1[2], a1[3]);
        if (!live) { p0.x = p0.y = p1.x = p1.y = 0u; }
        unsigned short* dp = S1 + ((row * 48 + Xp) << 3) + half;
        *(uint2*)(dp + pl0 * 7680)       = p0;   // ch o = kg*4..+3
        *(uint2*)(dp + (2 + pl0) * 7680) = p1;   // ch o = 16+kg*4..+3
    }
#pragma unroll
    for (int d = 0; d < 9; ++d) {              // conv3 weights prefetch (reuse wfA)
        wfA[d][0] = bc16(wp3[(d * 32 + l15) * 4 + kg]);
        wfA[d][1] = bc16(wp3[(d * 32 + 16 + l15) * 4 + kg]);
    }
    __syncthreads();

    // ---- conv2: 18 rows x 3 xtiles (X''<34 real) -> buf2 (aliases bufA) ----
    for (int i = wv; i < 54; i += 16) {
        int row = i / 3, xt = i - row * 3;
        int Xp = xt * 16 + l15;
        int base = kg * 960 + row * 48 + Xp;
        f32x4 a0 = {0.f,0.f,0.f,0.f}, a1 = {0.f,0.f,0.f,0.f};
#pragma unroll
        for (int d = 0; d < 9; ++d) {
            bf16x8 bfr = L1[base + (d / 3) * 48 + (d % 3)];
            a0 = MFMA(wfB[d][0], bfr, a0);
            a1 = MFMA(wfB[d][1], bfr, a1);
        }
        if (Xp < 34) {
            bool live = ((unsigned)(y0 - 1 + row) < 256u) && ((unsigned)(x0 - 1 + Xp) < 256u);
            uint2 p0, p1;
            p0.x = packbf(a0[0], a0[1]); p0.y = packbf(a0[2], a0[3]);
            p1.x = packbf(a1[0], a1[1]); p1.y = packbf(a1[2], a1[3]);
            if (!live) { p0.x = p0.y = p1.x = p1.y = 0u; }
            unsigned short* dp = SA + ((row * 34 + Xp) << 3) + half;
            *(uint2*)(dp + pl0 * 4896)       = p0;
            *(uint2*)(dp + (2 + pl0) * 4896) = p1;
        }
    }
    __syncthreads();

    // ---- conv3: 16 rows x 2 xtiles -> global fp32 NCHW ----
    for (int i = wv; i < 32; i += 16) {
        int row = i >> 1, xt = i & 1;
        int Xp = xt * 16 + l15;
        int base = kg * 612 + row * 34 + Xp;
        f32x4 a0 = {0.f,0.f,0.f,0.f}, a1 = {0.f,0.f,0.f,0.f};
#pragma unroll
        for (int d = 0; d < 9; ++d) {
            bf16x8 bfr = LA[base + (d / 3) * 34 + (d % 3)];
            a0 = MFMA(wfA[d][0], bfr, a0);
            a1 = MFMA(wfA[d][1], bfr, a1);
        }
        int gy = y0 + row, gx = x0 + Xp;
        float* dp = out + (((size_t)b * 32 + kg * 4) << 16) + ((size_t)gy << 8) + gx;
#pragma unroll
        for (int r2 = 0; r2 < 4; ++r2) {
            dp[(size_t)r2 << 16]        = a0[r2];
            dp[(size_t)(r2 + 16) << 16] = a1[r2];
        }
    }
}

extern "C" void kernel_launch(void* const* d_in, const int* in_sizes, int n_in,
                              void* d_out, int out_size, void* d_ws, size_t ws_size,
                              hipStream_t stream) {
    const float* x    = (const float*)d_in[0];
    const float* w_c1 = (const float*)d_in[1];
    const float* w_c2 = (const float*)d_in[2];
    const float* wt1  = (const float*)d_in[3];
    const float* wt2  = (const float*)d_in[4];
    const float* wt3  = (const float*)d_in[5];
    float* out = (float*)d_out;

    char* ws = (char*)d_ws;
    float* gap = (float*)ws;                                   // 512 f @0
    unsigned short* w1 = (unsigned short*)(ws + 4096);         // 294912 B each
    unsigned short* w2 = (unsigned short*)(ws + 4096 + 294912);
    unsigned short* w3 = (unsigned short*)(ws + 4096 + 2 * 294912);
    unsigned short* xbf = (unsigned short*)(ws + 1048576);     // 67108864 B

    hipMemsetAsync(gap, 0, 2048, stream);
    gap_cvt_kernel<<<dim3(64, 16), 256, 0, stream>>>(x, gap, xbf);
    assemble_kernel<<<dim3(16, 3), 256, 0, stream>>>(gap, w_c1, w_c2,
                                                     wt1, wt2, wt3, w1, w2, w3);
    fused_conv3<<<dim3(8, 16, 16), 1024, 0, stream>>>(xbf, w1, w2, w3, out);
}

// Round 11
// 374.590 us; speedup vs baseline: 1.6257x; 1.6257x over previous
//
#include <hip/hip_runtime.h>

typedef __attribute__((ext_vector_type(8))) short bf16x8;
typedef __attribute__((ext_vector_type(4))) float f32x4;

#define TEMP_ 30.0f
#define MFMA(A,B,C) __builtin_amdgcn_mfma_f32_16x16x32_bf16(A,B,C,0,0,0)

static __device__ inline unsigned short f2bf(float f) {
    unsigned u = __builtin_bit_cast(unsigned, f);
    u = (u + 0x7FFFu + ((u >> 16) & 1u)) >> 16;   // RNE
    return (unsigned short)u;
}
static __device__ inline unsigned packbf(float a, float b) {
    return (unsigned)f2bf(a) | ((unsigned)f2bf(b) << 16);
}
static __device__ inline bf16x8 bc16(uint4 v) { return __builtin_bit_cast(bf16x8, v); }

// ---------- kernel 1: GAP + fp32 NCHW -> bf16 NHWC transpose ----------
// grid (64, 16): 4-row slab per b; 256 thr (4 waves = 4 rows)
#define SM_S 1034   // per-c plane stride in shorts: spreads phase-B reads across banks
__global__ __launch_bounds__(256) void gap_cvt_kernel(
    const float* __restrict__ x, float* __restrict__ gap,
    unsigned short* __restrict__ xbf)        // [16][256][256][32] bf16
{
    __shared__ unsigned short sm[32 * SM_S];
    __shared__ float red[4][32];
    int b = blockIdx.y, ys = blockIdx.x * 4;
    int t = threadIdx.x, wv = t >> 6, ln = t & 63;

    const float* xb = x + (((size_t)b * 32) << 16) + ((size_t)(ys + wv) << 8) + ln * 4;
    float part[32];
#pragma unroll
    for (int c = 0; c < 32; ++c) {
        float4 v = *(const float4*)(xb + ((size_t)c << 16));
        part[c] = v.x + v.y + v.z + v.w;
        unsigned* wp = (unsigned*)&sm[c * SM_S + wv * 258 + ln * 4];
        wp[0] = packbf(v.x, v.y);
        wp[1] = packbf(v.z, v.w);
    }
#pragma unroll
    for (int c = 0; c < 32; ++c) {
#pragma unroll
        for (int off = 32; off; off >>= 1) part[c] += __shfl_xor(part[c], off);
    }
    if (ln == 0) {
#pragma unroll
        for (int c = 0; c < 32; ++c) red[wv][c] = part[c];
    }
    __syncthreads();
    if (t < 32) {
        float s = red[0][t] + red[1][t] + red[2][t] + red[3][t];
        atomicAdd(&gap[b * 32 + t], s * (1.f / 65536.f));
    }
    // phase B: coalesced NHWC write. g = it*256+t -> uint4 index base+g (1KB/wave)
    uint4* outp = (uint4*)xbf;
    size_t base = (((size_t)b << 16) + ((size_t)ys << 8)) << 2;
#pragma unroll
    for (int it = 0; it < 16; ++it) {
        int g = it * 256 + t;
        int cgq = g & 3, px = g >> 2;          // px 0..1023 in slab
        int y = px >> 8, xx = px & 255;
        unsigned short h[8];
#pragma unroll
        for (int i = 0; i < 8; ++i) h[i] = sm[(cgq * 8 + i) * SM_S + y * 258 + xx];
        uint4 v;
        v.x = (unsigned)h[0] | ((unsigned)h[1] << 16);
        v.y = (unsigned)h[2] | ((unsigned)h[3] << 16);
        v.z = (unsigned)h[4] | ((unsigned)h[5] << 16);
        v.w = (unsigned)h[6] | ((unsigned)h[7] << 16);
        outp[base + g] = v;
    }
}

// ------- control MLP + softmax + blended weights -> bf16 [b][9][o(32)][c(32)] -------
__global__ __launch_bounds__(256) void assemble_kernel(
    const float* __restrict__ gap,
    const float* __restrict__ w_c1,   // [8][32]
    const float* __restrict__ w_c2,   // [128][8]
    const float* __restrict__ wt1,    // [4][32][288], inner j = c*9 + dy*3+dx
    const float* __restrict__ wt2,
    const float* __restrict__ wt3,
    unsigned short* __restrict__ wo1,
    unsigned short* __restrict__ wo2,
    unsigned short* __restrict__ wo3)
{
    int b = blockIdx.x;
    int sel = blockIdx.y;
    int t = threadIdx.x;
    __shared__ float gap_s[32], h_s[8], logit_s[128], coeff_s[32][4];
    if (t < 32) gap_s[t] = gap[b * 32 + t];
    __syncthreads();
    if (t < 8) {
        float a = 0.f;
        for (int c = 0; c < 32; ++c) a += gap_s[c] * w_c1[t * 32 + c];
        h_s[t] = a > 0.f ? a : 0.f;
    }
    __syncthreads();
    if (t < 128) {
        float a = 0.f;
        for (int k = 0; k < 8; ++k) a += h_s[k] * w_c2[t * 8 + k];
        logit_s[t] = a * (1.0f / TEMP_);
    }
    __syncthreads();
    if (t < 32) {
        float m = -1e30f;
        for (int e = 0; e < 4; ++e) m = fmaxf(m, logit_s[t * 4 + e]);
        float ex[4], sum = 0.f;
        for (int e = 0; e < 4; ++e) { ex[e] = expf(logit_s[t * 4 + e] - m); sum += ex[e]; }
        for (int e = 0; e < 4; ++e) coeff_s[t][e] = ex[e] / sum;
    }
    __syncthreads();

    const float* wt = sel == 0 ? wt1 : (sel == 1 ? wt2 : wt3);
    unsigned short* wo = sel == 0 ? wo1 : (sel == 1 ? wo2 : wo3);

    for (int idx = t; idx < 9216; idx += 256) {   // idx = d*1024 + o*32 + c
        int d = idx >> 10;
        int o = (idx >> 5) & 31;
        int c = idx & 31;
        int j = c * 9 + d;
        float v = coeff_s[o][0] * wt[(0 * 32 + o) * 288 + j]
                + coeff_s[o][1] * wt[(1 * 32 + o) * 288 + j]
                + coeff_s[o][2] * wt[(2 * 32 + o) * 288 + j]
                + coeff_s[o][3] * wt[(3 * 32 + o) * 288 + j];
        wo[(size_t)b * 9216 + idx] = f2bf(v);
    }
}

// ------------- fused conv1->conv2->conv3, intermediates in LDS -------------
// PLANAR LDS: 4 planes of 8 channels (16B granule) per buffer -> conflict-free
// b128 reads (4x256B contiguous per wave) and uint2 writes.
// bufA: plane p at uint4 ofs p*836, [22][38].  buf1: 3344 + p*960, [20][48].
// buf2 (aliases bufA): p*612, [18][34].
// Chained pad=1: intermediates outside [0,256)^2 are ZEROED.
// grid (8,16,16), 512 thr (8 waves), LDS ~115KB -> 1 block/CU, 2 waves/SIMD.
// NOTE round-9 lesson: launch_bounds(1024,4) capped VGPR at 64 -> weight frags
// (~144 VGPR) spilled to scratch -> 661MB fetch. Keep (512,2): 92 VGPR, no spill.
__global__ __launch_bounds__(512, 2) void fused_conv3(
    const unsigned short* __restrict__ xbf,   // [16][256][256][32]
    const unsigned short* __restrict__ w1,    // [16][9][32][32]
    const unsigned short* __restrict__ w2,
    const unsigned short* __restrict__ w3,
    float* __restrict__ out)                  // [16][32][256][256]
{
    __shared__ uint4 lds[7192];   // [0,3344) bufA; [3344,7184) buf1; pad
    int b  = blockIdx.z;
    int x0 = blockIdx.x * 32, y0 = blockIdx.y * 16;
    int t  = threadIdx.x;
    int l15 = t & 15, kg = (t >> 4) & 3, wv = t >> 6;   // wv 0..7

    const uint4* wp1 = (const uint4*)(w1 + (size_t)b * 9216);
    const uint4* wp2 = (const uint4*)(w2 + (size_t)b * 9216);
    const uint4* wp3 = (const uint4*)(w3 + (size_t)b * 9216);

    bf16x8 wfA[9][2], wfB[9][2];
#pragma unroll
    for (int d = 0; d < 9; ++d) {              // conv1 weights
        wfA[d][0] = bc16(wp1[(d * 32 + l15) * 4 + kg]);
        wfA[d][1] = bc16(wp1[(d * 32 + 16 + l15) * 4 + kg]);
    }

    // stage 38x22 tile -> bufA planes. tau = px*4+cg keeps global reads coalesced;
    // LDS uint4 idx = cg*836 + px.
    const unsigned short* xb = xbf + (((size_t)b) << 16) * 32;
#pragma unroll
    for (int it = 0; it < 7; ++it) {
        int tau = it * 512 + t;
        if (tau < 3344) {
            int px = tau >> 2, cg = tau & 3;
            int y = px / 38, xx = px - y * 38;
            int gy = y0 - 3 + y, gx = x0 - 3 + xx;
            uint4 v = make_uint4(0u, 0u, 0u, 0u);
            if ((unsigned)gy < 256u && (unsigned)gx < 256u)
                v = *(const uint4*)(xb + ((((size_t)gy << 8) + gx) << 5) + (cg << 3));
            lds[cg * 836 + px] = v;
        }
    }
#pragma unroll
    for (int d = 0; d < 9; ++d) {              // conv2 weights prefetch
        wfB[d][0] = bc16(wp2[(d * 32 + l15) * 4 + kg]);
        wfB[d][1] = bc16(wp2[(d * 32 + 16 + l15) * 4 + kg]);
    }
    __syncthreads();

    const bf16x8* LA = (const bf16x8*)lds;
    const bf16x8* L1 = (const bf16x8*)(lds + 3344);
    unsigned short* SA = (unsigned short*)lds;
    unsigned short* S1 = (unsigned short*)(lds + 3344);
    int pl0 = kg >> 1, half = (kg & 1) << 2;   // write plane pair / 8B half

    // ---- conv1: 20 rows x 3 xtiles (48 wide; X'<36 real) ----
    for (int i = wv; i < 60; i += 8) {
        int row = i / 3, xt = i - row * 3;
        int Xp = xt * 16 + l15;
        int base = kg * 836 + row * 38 + Xp;
        f32x4 a0 = {0.f,0.f,0.f,0.f}, a1 = {0.f,0.f,0.f,0.f};
#pragma unroll
        for (int d = 0; d < 9; ++d) {
            bf16x8 bfr = LA[base + (d / 3) * 38 + (d % 3)];
            a0 = MFMA(wfA[d][0], bfr, a0);
            a1 = MFMA(wfA[d][1], bfr, a1);
        }
        bool live = ((unsigned)(y0 - 2 + row) < 256u) && ((unsigned)(x0 - 2 + Xp) < 256u);
        uint2 p0, p1;
        p0.x = packbf(a0[0], a0[1]); p0.y = packbf(a0[2], a0[3]);
        p1.x = packbf(a1[0], a1[1]); p1.y = packbf(a1[2], a1[3]);
        if (!live) { p0.x = p0.y = p1.x = p1.y = 0u; }
        unsigned short* dp = S1 + ((row * 48 + Xp) << 3) + half;
        *(uint2*)(dp + pl0 * 7680)       = p0;   // ch o = kg*4..+3
        *(uint2*)(dp + (2 + pl0) * 7680) = p1;   // ch o = 16+kg*4..+3
    }
#pragma unroll
    for (int d = 0; d < 9; ++d) {              // conv3 weights prefetch (reuse wfA)
        wfA[d][0] = bc16(wp3[(d * 32 + l15) * 4 + kg]);
        wfA[d][1] = bc16(wp3[(d * 32 + 16 + l15) * 4 + kg]);
    }
    __syncthreads();

    // ---- conv2: 18 rows x 3 xtiles (X''<34 real) -> buf2 (aliases bufA) ----
    for (int i = wv; i < 54; i += 8) {
        int row = i / 3, xt = i - row * 3;
        int Xp = xt * 16 + l15;
        int base = kg * 960 + row * 48 + Xp;
        f32x4 a0 = {0.f,0.f,0.f,0.f}, a1 = {0.f,0.f,0.f,0.f};
#pragma unroll
        for (int d = 0; d < 9; ++d) {
            bf16x8 bfr = L1[base + (d / 3) * 48 + (d % 3)];
            a0 = MFMA(wfB[d][0], bfr, a0);
            a1 = MFMA(wfB[d][1], bfr, a1);
        }
        if (Xp < 34) {
            bool live = ((unsigned)(y0 - 1 + row) < 256u) && ((unsigned)(x0 - 1 + Xp) < 256u);
            uint2 p0, p1;
            p0.x = packbf(a0[0], a0[1]); p0.y = packbf(a0[2], a0[3]);
            p1.x = packbf(a1[0], a1[1]); p1.y = packbf(a1[2], a1[3]);
            if (!live) { p0.x = p0.y = p1.x = p1.y = 0u; }
            unsigned short* dp = SA + ((row * 34 + Xp) << 3) + half;
            *(uint2*)(dp + pl0 * 4896)       = p0;
            *(uint2*)(dp + (2 + pl0) * 4896) = p1;
        }
    }
    __syncthreads();

    // ---- conv3: 16 rows x 2 xtiles -> global fp32 NCHW ----
    for (int i = wv; i < 32; i += 8) {
        int row = i >> 1, xt = i & 1;
        int Xp = xt * 16 + l15;
        int base = kg * 612 + row * 34 + Xp;
        f32x4 a0 = {0.f,0.f,0.f,0.f}, a1 = {0.f,0.f,0.f,0.f};
#pragma unroll
        for (int d = 0; d < 9; ++d) {
            bf16x8 bfr = LA[base + (d / 3) * 34 + (d % 3)];
            a0 = MFMA(wfA[d][0], bfr, a0);
            a1 = MFMA(wfA[d][1], bfr, a1);
        }
        int gy = y0 + row, gx = x0 + Xp;
        float* dp = out + (((size_t)b * 32 + kg * 4) << 16) + ((size_t)gy << 8) + gx;
#pragma unroll
        for (int r2 = 0; r2 < 4; ++r2) {
            dp[(size_t)r2 << 16]        = a0[r2];
            dp[(size_t)(r2 + 16) << 16] = a1[r2];
        }
    }
}

extern "C" void kernel_launch(void* const* d_in, const int* in_sizes, int n_in,
                              void* d_out, int out_size, void* d_ws, size_t ws_size,
                              hipStream_t stream) {
    const float* x    = (const float*)d_in[0];
    const float* w_c1 = (const float*)d_in[1];
    const float* w_c2 = (const float*)d_in[2];
    const float* wt1  = (const float*)d_in[3];
    const float* wt2  = (const float*)d_in[4];
    const float* wt3  = (const float*)d_in[5];
    float* out = (float*)d_out;

    char* ws = (char*)d_ws;
    float* gap = (float*)ws;                                   // 512 f @0
    unsigned short* w1 = (unsigned short*)(ws + 4096);         // 294912 B each
    unsigned short* w2 = (unsigned short*)(ws + 4096 + 294912);
    unsigned short* w3 = (unsigned short*)(ws + 4096 + 2 * 294912);
    unsigned short* xbf = (unsigned short*)(ws + 1048576);     // 67108864 B

    hipMemsetAsync(gap, 0, 2048, stream);
    gap_cvt_kernel<<<dim3(64, 16), 256, 0, stream>>>(x, gap, xbf);
    assemble_kernel<<<dim3(16, 3), 256, 0, stream>>>(gap, w_c1, w_c2,
                                                     wt1, wt2, wt3, w1, w2, w3);
    fused_conv3<<<dim3(8, 16, 16), 512, 0, stream>>>(xbf, w1, w2, w3, out);
}